// Round 1
// baseline (832.093 us; speedup 1.0000x reference)
//
#include <hip/hip_runtime.h>

#define N_NODES 40000
#define N_EDGES 640000

typedef __attribute__((ext_vector_type(8))) short short8;
typedef __attribute__((ext_vector_type(4))) float float4v;

__device__ inline short f2bf(float f) {
  unsigned u = __float_as_uint(f);
  unsigned r = (u + 0x7FFFu + ((u >> 16) & 1u)) >> 16;
  return (short)r;
}

// ---- convert + transpose weights to bf16: Wt[c][k] = bf16(W[k][c]) ----
__global__ void prep_w(const float* __restrict__ Wm, const float* __restrict__ We,
                       const float* __restrict__ Ws, short* __restrict__ WtM,
                       short* __restrict__ WtE, short* __restrict__ WtS) {
  int i = blockIdx.x * 256 + threadIdx.x;  // 40960 total
  if (i < 16384) {
    int c = i >> 7, k = i & 127;
    WtM[c * 128 + k] = f2bf(Wm[k * 128 + c]);
  } else if (i < 32768) {
    int j = i - 16384;
    int c = j >> 7, k = j & 127;
    WtE[c * 128 + k] = f2bf(We[k * 128 + c]);
  } else {
    int j = i - 32768;
    int c = j >> 7, k = j & 127;  // c in 0..63
    WtS[c * 128 + k] = f2bf(Ws[k * 64 + c]);
  }
}

// ---- generic row-tile GEMM: out[M, NT*16] = A[M,128] @ W[128, NT*16] + bias ----
// Wt is bf16 transposed [NT*16][128]. 64 rows per block (4 waves x 16 rows).
template <int NT>
__global__ __launch_bounds__(256) void gemm_rows(const float* __restrict__ A,
                                                 const short* __restrict__ Wt,
                                                 const float* __restrict__ bias,
                                                 float* __restrict__ out) {
  __shared__ short wt[NT * 16 * 136];
  for (int i = threadIdx.x; i < NT * 16 * 16; i += 256) {
    int c = i >> 4, j = i & 15;
    *(uint4*)&wt[c * 136 + j * 8] = ((const uint4*)Wt)[i];
  }
  __syncthreads();
  const int l = threadIdx.x & 63, w = threadIdx.x >> 6;
  const int lr = l & 15, q = l >> 4;
  const int row = blockIdx.x * 64 + w * 16 + lr;
  float4v acc[NT];
#pragma unroll
  for (int t = 0; t < NT; ++t) acc[t] = (float4v){0.f, 0.f, 0.f, 0.f};
  const float* ap = A + (size_t)row * 128 + q * 8;
#pragma unroll
  for (int s = 0; s < 4; ++s) {
    float4 a0 = *(const float4*)(ap + s * 32);
    float4 a1 = *(const float4*)(ap + s * 32 + 4);
    short8 af;
    af[0] = f2bf(a0.x); af[1] = f2bf(a0.y); af[2] = f2bf(a0.z); af[3] = f2bf(a0.w);
    af[4] = f2bf(a1.x); af[5] = f2bf(a1.y); af[6] = f2bf(a1.z); af[7] = f2bf(a1.w);
#pragma unroll
    for (int t = 0; t < NT; ++t) {
      short8 bf = *(const short8*)&wt[(t * 16 + lr) * 136 + s * 32 + q * 8];
      acc[t] = __builtin_amdgcn_mfma_f32_16x16x32_bf16(af, bf, acc[t], 0, 0, 0);
    }
  }
  const int orow = blockIdx.x * 64 + w * 16 + q * 4;
#pragma unroll
  for (int t = 0; t < NT; ++t) {
    int col = lr + 16 * t;
    float b = bias[col];
#pragma unroll
    for (int j = 0; j < 4; ++j)
      out[(size_t)(orow + j) * (NT * 16) + col] = acc[t][j] + b;
  }
}

// ---- fused edge kernel: le = ea@W_edge + b_edge (store), m = le + xm[src],
//      alpha[e,h] = leaky_relu(sum_c m[e,h*64+c]*att[h*64+c]) ----
__global__ __launch_bounds__(256) void edge_kernel(
    const float* __restrict__ ea, const short* __restrict__ WtE,
    const float* __restrict__ b_edge, const float* __restrict__ xm,
    const float* __restrict__ att, const int* __restrict__ src,
    float* __restrict__ le_out, float* __restrict__ alpha_out) {
  __shared__ short wt[128 * 136];
  __shared__ int sid[64];
  for (int i = threadIdx.x; i < 128 * 16; i += 256) {
    int c = i >> 4, j = i & 15;
    *(uint4*)&wt[c * 136 + j * 8] = ((const uint4*)WtE)[i];
  }
  if (threadIdx.x < 64) sid[threadIdx.x] = src[blockIdx.x * 64 + threadIdx.x];
  __syncthreads();
  const int l = threadIdx.x & 63, w = threadIdx.x >> 6;
  const int lr = l & 15, q = l >> 4;
  const int r0 = blockIdx.x * 64 + w * 16;
  float4v acc[8];
#pragma unroll
  for (int t = 0; t < 8; ++t) acc[t] = (float4v){0.f, 0.f, 0.f, 0.f};
  const float* ap = ea + (size_t)(r0 + lr) * 128 + q * 8;
#pragma unroll
  for (int s = 0; s < 4; ++s) {
    float4 a0 = *(const float4*)(ap + s * 32);
    float4 a1 = *(const float4*)(ap + s * 32 + 4);
    short8 af;
    af[0] = f2bf(a0.x); af[1] = f2bf(a0.y); af[2] = f2bf(a0.z); af[3] = f2bf(a0.w);
    af[4] = f2bf(a1.x); af[5] = f2bf(a1.y); af[6] = f2bf(a1.z); af[7] = f2bf(a1.w);
#pragma unroll
    for (int t = 0; t < 8; ++t) {
      short8 bf = *(const short8*)&wt[(t * 16 + lr) * 136 + s * 32 + q * 8];
      acc[t] = __builtin_amdgcn_mfma_f32_16x16x32_bf16(af, bf, acc[t], 0, 0, 0);
    }
  }
  const int rb = q * 4;
  int sidr[4];
#pragma unroll
  for (int j = 0; j < 4; ++j) sidr[j] = sid[w * 16 + rb + j];
  float p[8];
#pragma unroll
  for (int k = 0; k < 8; ++k) p[k] = 0.f;
#pragma unroll
  for (int t = 0; t < 8; ++t) {
    int col = lr + 16 * t;
    float b = b_edge[col];
    float av = att[col];
    int hp = (t >> 2) * 4;  // head = col>>6 = t>>2
#pragma unroll
    for (int j = 0; j < 4; ++j) {
      float lev = acc[t][j] + b;
      le_out[(size_t)(r0 + rb + j) * 128 + col] = lev;
      float mv = lev + xm[(size_t)sidr[j] * 128 + col];
      p[hp + j] += mv * av;
    }
  }
  // butterfly-reduce over the 16 lanes of each quad group
#pragma unroll
  for (int d = 1; d < 16; d <<= 1) {
#pragma unroll
    for (int k = 0; k < 8; ++k) p[k] += __shfl_xor(p[k], d);
  }
  if (lr < 8) {
    int j = lr >> 1, h = lr & 1;
    float v = p[h * 4 + j];
    alpha_out[(size_t)(r0 + rb + j) * 2 + h] = v > 0.f ? v : 0.2f * v;
  }
}

// ---- scatter-softmax: max pass (ordered-uint encoding) ----
__device__ inline unsigned enc_f(float v) {
  unsigned u = __float_as_uint(v);
  return (u & 0x80000000u) ? ~u : (u | 0x80000000u);
}
__device__ inline float dec_f(unsigned u) {
  unsigned v = (u & 0x80000000u) ? (u & 0x7FFFFFFFu) : ~u;
  return __uint_as_float(v);
}

__global__ void amax_k(const float* __restrict__ alpha, const int* __restrict__ dst,
                       unsigned* __restrict__ amx) {
  int i = blockIdx.x * 256 + threadIdx.x;  // 2E exact
  int e = i >> 1, h = i & 1;
  atomicMax(&amx[dst[e] * 2 + h], enc_f(alpha[i]));
}

__global__ void denom_k(float* __restrict__ alpha, const int* __restrict__ dst,
                        const unsigned* __restrict__ amx, float* __restrict__ den) {
  int i = blockIdx.x * 256 + threadIdx.x;  // 2E exact
  int e = i >> 1, h = i & 1;
  int d = dst[e];
  float mx = dec_f(amx[d * 2 + h]);
  float ex = __expf(alpha[i] - mx);
  alpha[i] = ex;  // overwrite with numerator
  unsafeAtomicAdd(&den[d * 2 + h], ex);
}

// ---- weighted scatter-add, head-mean folded in: one wave per edge ----
__global__ __launch_bounds__(256) void agg_k(const float* __restrict__ le,
                                             const float* __restrict__ xm,
                                             const float* __restrict__ ex,
                                             const float* __restrict__ den,
                                             const int* __restrict__ src,
                                             const int* __restrict__ dst,
                                             float* __restrict__ agg) {
  int w = threadIdx.x >> 6, l = threadIdx.x & 63;
  int e = blockIdx.x * 4 + w;
  int s = src[e], d = dst[e];
  float a0 = ex[e * 2 + 0] / (den[d * 2 + 0] + 1e-16f);
  float a1 = ex[e * 2 + 1] / (den[d * 2 + 1] + 1e-16f);
  float m0 = le[(size_t)e * 128 + l] + xm[(size_t)s * 128 + l];
  float m1 = le[(size_t)e * 128 + 64 + l] + xm[(size_t)s * 128 + 64 + l];
  unsafeAtomicAdd(&agg[(size_t)d * 64 + l], 0.5f * (m0 * a0 + m1 * a1));
}

// ---- final: out = agg_mean + xs ----
__global__ void out_k(const float* __restrict__ agg, const float* __restrict__ xs,
                      float* __restrict__ out) {
  int i = blockIdx.x * 256 + threadIdx.x;  // N*16 exact (float4 granules)
  float4 a = ((const float4*)agg)[i];
  float4 s = ((const float4*)xs)[i];
  float4 r;
  r.x = a.x + s.x; r.y = a.y + s.y; r.z = a.z + s.z; r.w = a.w + s.w;
  ((float4*)out)[i] = r;
}

extern "C" void kernel_launch(void* const* d_in, const int* in_sizes, int n_in,
                              void* d_out, int out_size, void* d_ws, size_t ws_size,
                              hipStream_t stream) {
  const float* x      = (const float*)d_in[0];
  const float* ea     = (const float*)d_in[1];
  const float* W_msg  = (const float*)d_in[2];
  const float* b_msg  = (const float*)d_in[3];
  const float* W_edge = (const float*)d_in[4];
  const float* b_edge = (const float*)d_in[5];
  const float* W_self = (const float*)d_in[6];
  const float* b_self = (const float*)d_in[7];
  const float* att    = (const float*)d_in[8];
  const int*   eidx   = (const int*)d_in[9];
  const int* src = eidx;
  const int* dst = eidx + N_EDGES;
  float* out_p = (float*)d_out;
  float* le_p  = out_p + (size_t)N_NODES * 64;

  char* ws = (char*)d_ws;
  short* WtM   = (short*)(ws);                 // 32768 B
  short* WtE   = (short*)(ws + 32768);         // 32768 B
  short* WtS   = (short*)(ws + 65536);         // 16384 B
  float* xm    = (float*)(ws + 81920);         // N*128*4 = 20,480,000 B
  float* xs    = (float*)(ws + 20561920);      // N*64*4  = 10,240,000 B
  float* alp   = (float*)(ws + 30801920);      // E*2*4   =  5,120,000 B
  unsigned* amx = (unsigned*)(ws + 35921920);  // N*2*4   =    320,000 B
  float* den   = (float*)(ws + 36241920);      // N*2*4   =    320,000 B
  float* agg   = (float*)(ws + 36561920);      // N*64*4  = 10,240,000 B
  // total 46,801,920 B

  // zero amx, den, agg in one shot (contiguous)
  hipMemsetAsync(ws + 35921920, 0, 10880000, stream);

  prep_w<<<160, 256, 0, stream>>>(W_msg, W_edge, W_self, WtM, WtE, WtS);
  gemm_rows<8><<<625, 256, 0, stream>>>(x, WtM, b_msg, xm);
  gemm_rows<4><<<625, 256, 0, stream>>>(x, WtS, b_self, xs);
  edge_kernel<<<10000, 256, 0, stream>>>(ea, WtE, b_edge, xm, att, src, le_p, alp);
  amax_k<<<5000, 256, 0, stream>>>(alp, dst, amx);
  denom_k<<<5000, 256, 0, stream>>>(alp, dst, amx, den);
  agg_k<<<160000, 256, 0, stream>>>(le_p, xm, alp, den, src, dst, agg);
  out_k<<<2500, 256, 0, stream>>>(agg, xs, out_p);
}